// Round 7
// baseline (340.924 us; speedup 1.0000x reference)
//
#include <hip/hip_runtime.h>
#include <stdint.h>

// Problem dims (fixed by the reference):
//   B=8192, P=2, L1=L2=9, N=25, F=128
//   x1: [B,2,9,128] f32, x2: [B,2,9,128] f32, cg: [9,9,25] f32
//   out: [B,1,2,25,128] f32
//
// out[b,0,0,n,f] = sum_{l,m} cg[l,m,n]*(x1e[l]*x2o[m] + x1o[l]*x2e[m])
// out[b,0,1,n,f] = sum_{l,m} cg[l,m,n]*(x1e[l]*x2o[m] + x1o[l]*x2o[m])
// (reference's eoo==eee bug reproduced: both channels share the x1e*x2o term)
//
// Round-5 (2nd resubmit; acquisition timed out twice): single-variable
// change vs round-4 — cg is read through an addrspace(4) ("constant")
// pointer aliasing the repacked __device__ buffer. Uniform address +
// constant addrspace forces the backend onto the SMEM pipe
// (s_load_dwordx*), eliminating ~1053 per-lane broadcast VMEM issues per
// thread that (per the round-2/3/4 timing pattern: 122/140/116 us, all
// ~3x above the 36-42 us VALU/HBM floors) were the real bottleneck. cg
// coefficients then live in SGPR pairs and feed v_pk_fma_f32 directly as
// the single allowed scalar operand.

#define B_DIM 8192
#define F_DIM 128
#define L_DIM 9
#define N_DIM 25
#define NROW 26                  // padded row stride (even -> 8B-aligned pairs)
#define NPAIR 13                 // 13 n-pairs per row (incl. zero pad col 25)

typedef __attribute__((ext_vector_type(2))) float v2f;
typedef const __attribute__((address_space(4))) float* cfp4;

__device__ __align__(16) float g_cgp[L_DIM * L_DIM * NROW];  // 8424 B

__global__ __launch_bounds__(256) void cg_prep(const float* __restrict__ cg) {
    // repack [81][25] -> [81][26] with zero pad in col 25
    for (int i = threadIdx.x; i < L_DIM * L_DIM * NROW; i += 256) {
        const int row = i / NROW;
        const int c   = i - row * NROW;
        g_cgp[i] = (c < N_DIM) ? cg[row * N_DIM + c] : 0.0f;
    }
}

__global__ __launch_bounds__(256) void tp_kernel(
    const float* __restrict__ x1,
    const float* __restrict__ x2,
    float* __restrict__ out)
{
    const int g = blockIdx.x * 256 + threadIdx.x;
    const int b = g >> 7;      // g / F_DIM
    const int f = g & 127;     // g % F_DIM

    const float* x1b = x1 + (size_t)b * 2 * L_DIM * F_DIM + f;
    const float* x2b = x2 + (size_t)b * 2 * L_DIM * F_DIM + f;

    // x2 parity slices; m-loop fully unrolled -> static register indices
    float x2e[L_DIM], x2o[L_DIM];
#pragma unroll
    for (int m = 0; m < L_DIM; ++m) {
        x2e[m] = x2b[m * F_DIM];               // p=0 (even)
        x2o[m] = x2b[(L_DIM + m) * F_DIM];     // p=1 (odd)
    }

    // n-pair accumulators: acc[q] = {out[2q], out[2q+1]}; q=12.y is the pad
    v2f acc0[NPAIR], acc1[NPAIR];
#pragma unroll
    for (int q = 0; q < NPAIR; ++q) { acc0[q] = (v2f)(0.0f); acc1[q] = (v2f)(0.0f); }

    // Constant-addrspace alias of the repacked cg: uniform address +
    // addrspace(4) => s_load_dwordx* on the SMEM pipe (scalar cache).
    const cfp4 cgp = (cfp4)(uintptr_t)&g_cgp[0];

    // Outer l loop NOT unrolled: body ~300 insts, I$-friendly.
#pragma unroll 1
    for (int l = 0; l < L_DIM; ++l) {
        const float x1e = x1b[l * F_DIM];
        const float x1o = x1b[(L_DIM + l) * F_DIM];
        const int cl = l * (L_DIM * NROW);
#pragma unroll
        for (int m = 0; m < L_DIM; ++m) {
            // t shared between channels (reference's eoo==eee bug)
            const float t  = x1e * x2o[m];
            const float s0 = fmaf(x1o, x2e[m], t);   // ch0: eee+ooe
            const float s1 = fmaf(x1o, x2o[m], t);   // ch1: eoo+oeo
            v2f s0v; s0v.x = s0; s0v.y = s0;         // splat once, reuse x13
            v2f s1v; s1v.x = s1; s1v.y = s1;
            const int cm = cl + m * NROW;
#pragma unroll
            for (int q = 0; q < NPAIR; ++q) {
                v2f c2;                              // SGPR pair {cg[2q],cg[2q+1]}
                c2.x = cgp[cm + 2 * q];
                c2.y = cgp[cm + 2 * q + 1];
                acc0[q] = __builtin_elementwise_fma(c2, s0v, acc0[q]);
                acc1[q] = __builtin_elementwise_fma(c2, s1v, acc1[q]);
            }
        }
    }

    // out[b,0,ch,n,f] -> ((b*2 + ch)*25 + n)*128 + f
    float* ob = out + (size_t)b * 2 * N_DIM * F_DIM + f;
#pragma unroll
    for (int q = 0; q < NPAIR; ++q) {
        __builtin_nontemporal_store(acc0[q].x, ob + (2 * q) * F_DIM);
        __builtin_nontemporal_store(acc1[q].x, ob + (N_DIM + 2 * q) * F_DIM);
        if (q < NPAIR - 1) {  // q=12.y is the pad lane -> not stored
            __builtin_nontemporal_store(acc0[q].y, ob + (2 * q + 1) * F_DIM);
            __builtin_nontemporal_store(acc1[q].y, ob + (N_DIM + 2 * q + 1) * F_DIM);
        }
    }
}

extern "C" void kernel_launch(void* const* d_in, const int* in_sizes, int n_in,
                              void* d_out, int out_size, void* d_ws, size_t ws_size,
                              hipStream_t stream) {
    (void)in_sizes; (void)n_in; (void)out_size; (void)d_ws; (void)ws_size;
    const float* x1 = (const float*)d_in[0];
    const float* x2 = (const float*)d_in[1];
    const float* cg = (const float*)d_in[2];
    float* out = (float*)d_out;

    // 1) repack cg into padded __device__ array (stream-ordered before main)
    cg_prep<<<1, 256, 0, stream>>>(cg);

    // 2) main: B*F threads, one (b,f) each: 8192*128/256 = 4096 blocks
    const int threads = 256;
    const int blocks  = (B_DIM * F_DIM) / threads;
    tp_kernel<<<blocks, threads, 0, stream>>>(x1, x2, out);
}